// Round 1
// baseline (22874.817 us; speedup 1.0000x reference)
//
#include <hip/hip_runtime.h>
#include <cstdint>
#include <cstddef>

// Problem constants (fixed by the reference)
#define DD 1024
#define TT 2048
#define NL 4
// Recurrence: 256 blocks x 256 threads (4 waves), wave-per-column.
#define NBLK 256
#define NTHR 256
// x-part GEMM tiles
#define GT 128
#define GC 128
#define GK 16

__device__ __forceinline__ float fast_tanh(float x) {
  float e = __expf(2.f * x);
  return 1.f - 2.f / (e + 1.f);
}

// 16B agent-scope load: bypasses the (non-coherent) per-XCD L2.
__device__ __forceinline__ float4 agent_load16(const float* p) {
  float4 r;
  asm volatile("global_load_dwordx4 %0, %1, off sc1\n\t"
               "s_waitcnt vmcnt(0)"
               : "=v"(r) : "v"(p) : "memory");
  return r;
}

// DPP-based wave64 all-reduce add.
// Steps 1-4: xor1 (quad_perm[1,0,3,2]), xor2 (quad_perm[2,3,0,1]),
// half-row mirror, row mirror. These rely on the invariant that after
// step k every lane of a 2^k group holds the group sum, so mirror
// partners (i^7, i^15) carry exactly the other subgroup's sum.
// Steps 5-6: cross-row via __shfl_xor (ds_bpermute) -> all lanes hold total.
template <int CTRL>
__device__ __forceinline__ float dpp_add(float x) {
  int y = __builtin_amdgcn_update_dpp(0, __float_as_int(x), CTRL, 0xf, 0xf, true);
  return x + __int_as_float(y);
}
__device__ __forceinline__ float wave_allreduce_add(float x) {
  x = dpp_add<0xB1>(x);    // quad_perm [1,0,3,2]  : + lane^1
  x = dpp_add<0x4E>(x);    // quad_perm [2,3,0,1]  : + lane^2
  x = dpp_add<0x141>(x);   // row_half_mirror      : + lane^7 (other quad's sum)
  x = dpp_add<0x140>(x);   // row_mirror           : + lane^15 (other 8-group's sum)
  x += __shfl_xor(x, 16, 64);
  x += __shfl_xor(x, 32, 64);
  return x;
}

__global__ __launch_bounds__(1024) void prep_kernel(
    const float* __restrict__ sp, const float* __restrict__ rn_p,
    const float* __restrict__ w, const float* __restrict__ b,
    float* __restrict__ X0) {
  int i = blockIdx.x * blockDim.x + threadIdx.x;   // over T*D
  float rn = rn_p[0];
  int c = i & (DD - 1);
  X0[i] = sp[i] + rn * w[c] + b[c];
}

// ZX[t][piece*1024 + c] = sum_k X[t][k] * W[piece][k][c] + b[piece][c]
__global__ __launch_bounds__(256) void xgemm_kernel(
    const float* __restrict__ X,    // [TT, DD]
    const float* __restrict__ Wf1, const float* __restrict__ Wf2,
    const float* __restrict__ Wta, const float* __restrict__ Wtb,
    const float* __restrict__ bf1, const float* __restrict__ bf2,
    const float* __restrict__ bta, const float* __restrict__ btb,
    float* __restrict__ ZX, int layer)
{
  __shared__ float As[GK][GT + 4];
  __shared__ float Bs[GK][GC + 4];

  const int tid = threadIdx.x;
  const int ct = blockIdx.x;                 // col tile 0..31
  const int rt = blockIdx.y;                 // row tile 0..15
  const int c0 = ct * GC;
  const int B  = c0 >> 10;
  const int cc0 = c0 & (DD - 1);
  const float* Wsel = (B == 0) ? Wf1 : (B == 1) ? Wf2 : (B == 2) ? Wta : Wtb;
  const float* bsel = (B == 0) ? bf1 : (B == 1) ? bf2 : (B == 2) ? bta : btb;
  const float* Wb = Wsel + (size_t)layer * 2 * DD * DD;   // x rows 0..1023
  const float* bb = bsel + (size_t)layer * DD + cc0;

  const int ty = tid >> 4, tx = tid & 15;

  float acc[8][8];
#pragma unroll
  for (int i = 0; i < 8; ++i)
#pragma unroll
    for (int j = 0; j < 8; ++j) acc[i][j] = 0.f;

  for (int k0 = 0; k0 < DD; k0 += GK) {
#pragma unroll
    for (int j = 0; j < 2; ++j) {
      int idx = j * 256 + tid;
      int r = idx >> 2;
      int kq = (idx & 3) * 4;
      float4 v = *(const float4*)&X[(size_t)(rt * GT + r) * DD + k0 + kq];
      As[kq + 0][r] = v.x; As[kq + 1][r] = v.y;
      As[kq + 2][r] = v.z; As[kq + 3][r] = v.w;
    }
#pragma unroll
    for (int j = 0; j < 2; ++j) {
      int idx = j * 256 + tid;
      int kk = idx >> 5;
      int cq = (idx & 31) * 4;
      *(float4*)&Bs[kk][cq] =
          *(const float4*)&Wb[(size_t)(k0 + kk) * DD + cc0 + cq];
    }
    __syncthreads();
#pragma unroll
    for (int k = 0; k < GK; ++k) {
      float a[8], bv[8];
      *(float4*)&a[0]  = *(const float4*)&As[k][ty * 8];
      *(float4*)&a[4]  = *(const float4*)&As[k][ty * 8 + 4];
      *(float4*)&bv[0] = *(const float4*)&Bs[k][tx * 8];
      *(float4*)&bv[4] = *(const float4*)&Bs[k][tx * 8 + 4];
#pragma unroll
      for (int i = 0; i < 8; ++i)
#pragma unroll
        for (int j = 0; j < 8; ++j) acc[i][j] = fmaf(a[i], bv[j], acc[i][j]);
    }
    __syncthreads();
  }

  float bias[8];
#pragma unroll
  for (int j = 0; j < 8; ++j) bias[j] = bb[tx * 8 + j];
#pragma unroll
  for (int i = 0; i < 8; ++i) {
    int t = rt * GT + ty * 8 + i;
    float4 o0 = make_float4(acc[i][0] + bias[0], acc[i][1] + bias[1],
                            acc[i][2] + bias[2], acc[i][3] + bias[3]);
    float4 o1 = make_float4(acc[i][4] + bias[4], acc[i][5] + bias[5],
                            acc[i][6] + bias[6], acc[i][7] + bias[7]);
    *(float4*)&ZX[(size_t)t * 4096 + c0 + tx * 8]     = o0;
    *(float4*)&ZX[(size_t)t * 4096 + c0 + tx * 8 + 4] = o1;
  }
}

// h-part recurrence, wave-per-column with register-resident W_h.
//
// 256 blocks x 4 waves. Wave w of block bid owns output column
// col = bid*4 + w and computes ALL FOUR z-pieces (f1, f2, ta, tb) for it:
// lane ln holds the 16 W_h weights for rows {g*256 + ln*4 + j} per piece
// (64 VGPRs), reads h_{t-1} from a double-buffered LDS broadcast, does
// 64 FMAs into 4 partial sums, DPP-allreduces them, applies the gate, and
// immediately stores h(t)[col] (4B agent-scope) to R replicated buffers.
// All 256 threads then poll the full h(t) vector (16B/lane, per-lane
// early-out) from replica (bid & (R-1)) into the other LDS buffer.
// One __syncthreads per step (double buffering removes the second).
__global__ __launch_bounds__(NTHR, 1) void recur_kernel(
    const float* __restrict__ ZX,   // [TT, 4096], x-part incl. bias
    float* __restrict__ Hout,       // [TT, DD], NaN-prefilled
    float* __restrict__ REP,        // [R-1][TT, DD], NaN-prefilled
    int R,                          // replicas, power of 2, >=1
    const float* __restrict__ Wf1, const float* __restrict__ Wf2,
    const float* __restrict__ Wta, const float* __restrict__ Wtb,
    const float* __restrict__ dt_p, int layer,
    float* __restrict__ out_last)
{
  __shared__ __align__(16) float hbuf[2][DD];   // 8 KB double buffer

  const int tid = threadIdx.x;
  const int w   = tid >> 6;            // wave 0..3
  const int ln  = tid & 63;
  const int bid = blockIdx.x;
  const int col = bid * 4 + w;
  const float dtv = dt_p[0];

  const size_t off = (size_t)layer * 2 * DD * DD;
  const float* Wp[4] = { Wf1 + off, Wf2 + off, Wta + off, Wtb + off };

  // Weight preload: piece B, h-rows g*256 + ln*4 + j (j=0..3), column col.
  // Scattered scalar loads, once per layer (~10-30 us, off the hot loop).
  float wreg[4][16];
#pragma unroll
  for (int B = 0; B < 4; ++B) {
#pragma unroll
    for (int g = 0; g < 4; ++g) {
      const float* p = Wp[B] + (size_t)(DD + g * 256 + ln * 4) * DD + col;
      wreg[B][g * 4 + 0] = p[0 * DD];
      wreg[B][g * 4 + 1] = p[1 * DD];
      wreg[B][g * 4 + 2] = p[2 * DD];
      wreg[B][g * 4 + 3] = p[3 * DD];
    }
  }

  // This block reads replica (bid & (R-1)); producer lanes 0..R-1 write
  // replica ln (replica 0 = Hout, also the next layer's xgemm input).
  const int rsel = bid & (R - 1);
  const float* hread = (rsel == 0) ? Hout : REP + (size_t)(rsel - 1) * TT * DD;

  // h_{-1} = 0 in buffer 0; ZX(t=0) prefetch (lane ln<4 holds piece ln).
  *(float4*)&hbuf[0][tid * 4] = make_float4(0.f, 0.f, 0.f, 0.f);
  float zx_c = 0.f, zx_n = 0.f;
  if (ln < 4) zx_c = ZX[(size_t)ln * 1024 + col];
  __syncthreads();

  for (int t = 0; t < TT; ++t) {
    const float* rbuf = hbuf[t & 1];

    // Dot: 4 pieces x 16 rows per lane; zx folded into lane B's partial.
    float a0 = (ln == 0) ? zx_c : 0.f;
    float a1 = (ln == 1) ? zx_c : 0.f;
    float a2 = (ln == 2) ? zx_c : 0.f;
    float a3 = (ln == 3) ? zx_c : 0.f;
#pragma unroll
    for (int g = 0; g < 4; ++g) {
      float4 h4 = *(const float4*)&rbuf[g * 256 + ln * 4];
      a0 = fmaf(h4.x, wreg[0][4 * g + 0], a0);
      a0 = fmaf(h4.y, wreg[0][4 * g + 1], a0);
      a0 = fmaf(h4.z, wreg[0][4 * g + 2], a0);
      a0 = fmaf(h4.w, wreg[0][4 * g + 3], a0);
      a1 = fmaf(h4.x, wreg[1][4 * g + 0], a1);
      a1 = fmaf(h4.y, wreg[1][4 * g + 1], a1);
      a1 = fmaf(h4.z, wreg[1][4 * g + 2], a1);
      a1 = fmaf(h4.w, wreg[1][4 * g + 3], a1);
      a2 = fmaf(h4.x, wreg[2][4 * g + 0], a2);
      a2 = fmaf(h4.y, wreg[2][4 * g + 1], a2);
      a2 = fmaf(h4.z, wreg[2][4 * g + 2], a2);
      a2 = fmaf(h4.w, wreg[2][4 * g + 3], a2);
      a3 = fmaf(h4.x, wreg[3][4 * g + 0], a3);
      a3 = fmaf(h4.y, wreg[3][4 * g + 1], a3);
      a3 = fmaf(h4.z, wreg[3][4 * g + 2], a3);
      a3 = fmaf(h4.w, wreg[3][4 * g + 3], a3);
    }

    a0 = wave_allreduce_add(a0);   // z_f1
    a1 = wave_allreduce_add(a1);   // z_f2
    a2 = wave_allreduce_add(a2);   // z_ta
    a3 = wave_allreduce_add(a3);   // z_tb

    float f1 = fast_tanh(a0);
    float f2 = fast_tanh(a1);
    float g  = 1.f / (1.f + __expf(a2 * dtv - a3));
    float h  = fmaf(g, f1 - f2, f2);

    // Store h(t)[col] to R replicas (4B agent-scope, one lane per replica).
    if (ln < R) {
      float* dst = (ln == 0) ? Hout : REP + (size_t)(ln - 1) * TT * DD;
      __hip_atomic_store(&dst[(size_t)t * DD + col], h,
                         __ATOMIC_RELAXED, __HIP_MEMORY_SCOPE_AGENT);
    }
    if (t == TT - 1 && out_last != nullptr && ln == 0) out_last[col] = h;

    // Prefetch ZX(t+1) so its L2 latency hides under the poll.
    if (ln < 4 && t + 1 < TT) zx_n = ZX[(size_t)(t + 1) * 4096 + ln * 1024 + col];

    // Poll h(t) (all 256 threads, 16B each) into the other buffer.
    if (t < TT - 1) {
      const float* src = &hread[(size_t)t * DD + tid * 4];
      float4 v = make_float4(0.f, 0.f, 0.f, 0.f);
      bool ok = false;
      int guard = 0;
      while (true) {
        if (!ok) {                      // per-lane early-out: done lanes stop re-loading
          v = agent_load16(src);
          unsigned x0 = __float_as_uint(v.x) & 0x7fffffffu;
          unsigned x1 = __float_as_uint(v.y) & 0x7fffffffu;
          unsigned x2 = __float_as_uint(v.z) & 0x7fffffffu;
          unsigned x3 = __float_as_uint(v.w) & 0x7fffffffu;
          ok = (x0 <= 0x7f800000u) && (x1 <= 0x7f800000u) &&
               (x2 <= 0x7f800000u) && (x3 <= 0x7f800000u);
        }
        if (__all(ok)) break;
        if (++guard > (1 << 22)) break;
      }
      *(float4*)&hbuf[(t + 1) & 1][tid * 4] = v;
    }
    __syncthreads();
    zx_c = zx_n;
  }
}

extern "C" void kernel_launch(void* const* d_in, const int* in_sizes, int n_in,
                              void* d_out, int out_size, void* d_ws, size_t ws_size,
                              hipStream_t stream) {
  const float* sp  = (const float*)d_in[0];
  const float* rn  = (const float*)d_in[1];
  const float* dt  = (const float*)d_in[2];
  const float* rw  = (const float*)d_in[3];
  const float* rb  = (const float*)d_in[4];
  const float* Wf1 = (const float*)d_in[5];
  const float* bf1 = (const float*)d_in[6];
  const float* Wf2 = (const float*)d_in[7];
  const float* bf2 = (const float*)d_in[8];
  const float* Wta = (const float*)d_in[9];
  const float* bta = (const float*)d_in[10];
  const float* Wtb = (const float*)d_in[11];
  const float* btb = (const float*)d_in[12];

  float* ws = (float*)d_ws;
  float* A   = ws;                          // [TT, DD]
  float* Bb  = ws + (size_t)TT * DD;        // [TT, DD]
  float* ZX  = ws + (size_t)2 * TT * DD;    // [TT, 4096]
  float* REP = ws + (size_t)2 * TT * DD + (size_t)TT * 4096;  // [R-1][TT,DD]
  float* out = (float*)d_out;
  const size_t seqBytes = sizeof(float) * TT * DD;
  const size_t baseBytes = (size_t)(2 * TT * DD + TT * 4096) * sizeof(float);

  // Adaptive replica count (power of 2, max 8), limited by workspace size.
  // ws_size is constant across calls -> same work every call.
  int R = 1;
  for (int cand = 8; cand > 1; cand >>= 1)
    if (baseBytes + (size_t)(cand - 1) * seqBytes <= ws_size) { R = cand; break; }
  const size_t repBytes = (size_t)(R - 1) * seqBytes;

  dim3 ggrid(32, 16);

#define LAYER(lyr, Xbuf, Hbuf, lastout)                                        \
  do {                                                                         \
    (void)hipMemsetAsync(Hbuf, 0xFF, seqBytes, stream);                        \
    if (R > 1) { (void)hipMemsetAsync(REP, 0xFF, repBytes, stream); }          \
    xgemm_kernel<<<ggrid, 256, 0, stream>>>(Xbuf, Wf1, Wf2, Wta, Wtb,          \
        bf1, bf2, bta, btb, ZX, lyr);                                          \
    recur_kernel<<<NBLK, NTHR, 0, stream>>>(ZX, Hbuf, REP, R, Wf1, Wf2,        \
        Wta, Wtb, dt, lyr, lastout);                                           \
  } while (0)

  // L0: X0 -> A; h-seq -> Bb
  prep_kernel<<<(TT * DD) / 1024, 1024, 0, stream>>>(sp, rn, rw, rb, A);
  LAYER(0, A, Bb, nullptr);
  LAYER(1, Bb, A, nullptr);
  LAYER(2, A, Bb, nullptr);
  LAYER(3, Bb, A, out);
#undef LAYER
}

// Round 2
// 22621.754 us; speedup vs baseline: 1.0112x; 1.0112x over previous
//
#include <hip/hip_runtime.h>
#include <cstdint>
#include <cstddef>

// Problem constants (fixed by the reference)
#define DD 1024
#define TT 2048
#define NL 4
#define CH 128              // chunk length (timesteps) for pipelined x-GEMV
#define NCH (TT / CH)       // 16 chunks
#define NTHR 256            // 4 waves per block
#define PBLK (NL * 256)     // 1024 blocks, 4 per CU (all co-resident)
#define GUARD_LIM (1 << 20) // poll guard; substitute zeros on trip (no hang)

__device__ __forceinline__ float fast_tanh(float x) {
  float e = __expf(2.f * x);
  return 1.f - 2.f / (e + 1.f);
}

// 16B agent-scope load: bypasses the (non-coherent) per-XCD L2.
__device__ __forceinline__ float4 agent_load16(const float* p) {
  float4 r;
  asm volatile("global_load_dwordx4 %0, %1, off sc1\n\t"
               "s_waitcnt vmcnt(0)"
               : "=v"(r) : "v"(p) : "memory");
  return r;
}
// 16B agent-scope store as two 8B atomic stores (4B-granule atomicity is all
// the NaN-poll protocol needs; half-visible granule still has NaN words).
__device__ __forceinline__ void agent_store16(float* p, float4 v) {
  unsigned long long lo =
      ((unsigned long long)__float_as_uint(v.y) << 32) | __float_as_uint(v.x);
  unsigned long long hi =
      ((unsigned long long)__float_as_uint(v.w) << 32) | __float_as_uint(v.z);
  __hip_atomic_store((unsigned long long*)p, lo,
                     __ATOMIC_RELAXED, __HIP_MEMORY_SCOPE_AGENT);
  __hip_atomic_store(((unsigned long long*)p) + 1, hi,
                     __ATOMIC_RELAXED, __HIP_MEMORY_SCOPE_AGENT);
}

// DPP-based wave64 all-reduce add (4 DPP hops + 2 ds_bpermute hops).
template <int CTRL>
__device__ __forceinline__ float dpp_add(float x) {
  int y = __builtin_amdgcn_update_dpp(0, __float_as_int(x), CTRL, 0xf, 0xf, true);
  return x + __int_as_float(y);
}
__device__ __forceinline__ float wave_allreduce_add(float x) {
  x = dpp_add<0xB1>(x);    // quad_perm [1,0,3,2]  : + lane^1
  x = dpp_add<0x4E>(x);    // quad_perm [2,3,0,1]  : + lane^2
  x = dpp_add<0x141>(x);   // row_half_mirror      : + lane^7
  x = dpp_add<0x140>(x);   // row_mirror           : + lane^15
  x += __shfl_xor(x, 16, 64);
  x += __shfl_xor(x, 32, 64);
  return x;
}

__global__ __launch_bounds__(1024) void prep_kernel(
    const float* __restrict__ sp, const float* __restrict__ rn_p,
    const float* __restrict__ w, const float* __restrict__ b,
    float* __restrict__ X0) {
  int i = blockIdx.x * blockDim.x + threadIdx.x;   // over T*D
  float rn = rn_p[0];
  int c = i & (DD - 1);
  X0[i] = sp[i] + rn * w[c] + b[c];
}

// Persistent pipelined kernel: all 4 layers run concurrently (layer l lags
// layer l-1 by ~1 chunk). Block b: layer l = b&3, column group grp = b>>2
// (columns grp*4..grp*4+3). Per chunk:
//   Phase A (GEMV): zx[t][p*4+c] = bias + sum_k x_l(t)[k]*Wx[p][k][col]
//     for the chunk's 128 timesteps, x_l = X0 (l=0) or h_{l-1} (NaN-polled).
//   Phase B (recurrence): 128 steps; wave w owns column grp*4+w, h-part
//     weights in 16 named float4 VGPRs; DPP allreduce; gate; LDS-gather the
//     4 waves' h into one 16B agent store per replica; all threads poll the
//     full h(t) vector into a double-buffered LDS broadcast.
__global__ __launch_bounds__(NTHR, 4) void persist_kernel(
    const float* __restrict__ X0,   // [TT, DD] (valid at launch)
    float* __restrict__ HB,         // [NL*R][TT, DD], NaN-prefilled
    int R,                          // replicas per layer, power of 2, >=1
    const float* __restrict__ Wf1, const float* __restrict__ Wf2,
    const float* __restrict__ Wta, const float* __restrict__ Wtb,
    const float* __restrict__ bf1, const float* __restrict__ bf2,
    const float* __restrict__ bta, const float* __restrict__ btb,
    const float* __restrict__ dt_p,
    float* __restrict__ out_last)   // [DD], written by layer 3 at t=TT-1
{
  __shared__ __align__(16) float hbuf[2][DD];   // 8 KB h double buffer
  __shared__ float zxbuf[CH][16];               // 8 KB per-chunk x-part
  __shared__ float Xs[16][132];                 // GEMV x tile (transposed)
  __shared__ float Ws[16][16];                  // GEMV weight tile
  __shared__ __align__(16) float hq[4];         // h gather across waves

  const int tid = threadIdx.x;
  const int w   = tid >> 6;             // wave 0..3 = column offset
  const int ln  = tid & 63;
  const int l   = blockIdx.x & 3;       // layer
  const int grp = blockIdx.x >> 2;      // column group 0..255
  const int col = grp * 4 + w;
  const float dtv = dt_p[0];

  const size_t woff = (size_t)l * 2 * DD * DD;

  // ---- h-part weight preload into 16 NAMED float4 regs (64 VGPRs).
  // Component j of (piece P, group g) = W[P][DD + g*256 + ln*4 + j][col].
  float4 wA0, wA1, wA2, wA3, wB0, wB1, wB2, wB3;
  float4 wC0, wC1, wC2, wC3, wD0, wD1, wD2, wD3;
#define LOADW(dst, base, g) do { \
    const float* p_ = (base) + (size_t)(DD + (g) * 256 + ln * 4) * DD + col; \
    dst = make_float4(p_[0], p_[DD], p_[2 * DD], p_[3 * DD]); \
  } while (0)
  {
    const float* W_ = Wf1 + woff;
    LOADW(wA0, W_, 0); LOADW(wA1, W_, 1); LOADW(wA2, W_, 2); LOADW(wA3, W_, 3);
    W_ = Wf2 + woff;
    LOADW(wB0, W_, 0); LOADW(wB1, W_, 1); LOADW(wB2, W_, 2); LOADW(wB3, W_, 3);
    W_ = Wta + woff;
    LOADW(wC0, W_, 0); LOADW(wC1, W_, 1); LOADW(wC2, W_, 2); LOADW(wC3, W_, 3);
    W_ = Wtb + woff;
    LOADW(wD0, W_, 0); LOADW(wD1, W_, 1); LOADW(wD2, W_, 2); LOADW(wD3, W_, 3);
  }
#undef LOADW

  // ---- GEMV thread mapping: tx = z-col (piece p = tx>>2, col ofs tx&3),
  // ty = row-group of 8 chunk rows.
  const int tx = tid & 15;
  const int ty = tid >> 4;
  const int p  = tx >> 2;
  const float* Wxp = ((p == 0) ? Wf1 : (p == 1) ? Wf2 : (p == 2) ? Wta : Wtb) + woff;
  const float* bsp = ((p == 0) ? bf1 : (p == 1) ? bf2 : (p == 2) ? bta : btb)
                     + (size_t)l * DD;
  const int colx = grp * 4 + (tx & 3);
  const float biasv = bsp[colx];

  // Replica selection: this block reads replica (grp & (R-1)) of both its
  // own layer (recurrence polls) and layer l-1 (GEMV x reads).
  const int rsel = grp & (R - 1);
  const float* hread = HB + (size_t)(l * R + rsel) * TT * DD;
  const float* xbase = (l == 0) ? X0 : HB + (size_t)((l - 1) * R + rsel) * TT * DD;

  // h_{-1} = 0
  *(float4*)&hbuf[0][tid * 4] = make_float4(0.f, 0.f, 0.f, 0.f);
  __syncthreads();

#pragma unroll 1
  for (int c = 0; c < NCH; ++c) {
    // ================= Phase A: chunk x-GEMV =================
    float acc[8];
#pragma unroll
    for (int i = 0; i < 8; ++i) acc[i] = 0.f;

#pragma unroll 1
    for (int k0 = 0; k0 < DD; k0 += 16) {
      // Weight tile [16k][16z]: one float per thread.
      Ws[ty][tx] = Wxp[(size_t)(k0 + ty) * DD + colx];
      // X tile [16k][128t] (transposed): 2 x 16B granules per thread,
      // NaN-polled for l>=1 (h_{l-1} produced concurrently).
#pragma unroll
      for (int g2 = 0; g2 < 2; ++g2) {
        int gi  = tid * 2 + g2;        // 0..511
        int row = gi >> 2;             // chunk row 0..127
        int q   = gi & 3;              // k-quad
        const float* src = xbase + (size_t)(c * CH + row) * DD + k0 + q * 4;
        float4 v;
        if (l == 0) {
          v = *(const float4*)src;
        } else {
          int guard = 0;
          while (true) {
            v = agent_load16(src);
            unsigned x0 = __float_as_uint(v.x) & 0x7fffffffu;
            unsigned x1 = __float_as_uint(v.y) & 0x7fffffffu;
            unsigned x2 = __float_as_uint(v.z) & 0x7fffffffu;
            unsigned x3 = __float_as_uint(v.w) & 0x7fffffffu;
            if ((x0 <= 0x7f800000u) && (x1 <= 0x7f800000u) &&
                (x2 <= 0x7f800000u) && (x3 <= 0x7f800000u)) break;
            if (++guard > GUARD_LIM) { v = make_float4(0.f, 0.f, 0.f, 0.f); break; }
          }
        }
        Xs[q * 4 + 0][row] = v.x; Xs[q * 4 + 1][row] = v.y;
        Xs[q * 4 + 2][row] = v.z; Xs[q * 4 + 3][row] = v.w;
      }
      __syncthreads();
#pragma unroll
      for (int kk = 0; kk < 16; ++kk) {
        float wv = Ws[kk][tx];
        float4 x0 = *(const float4*)&Xs[kk][ty * 8];
        float4 x1 = *(const float4*)&Xs[kk][ty * 8 + 4];
        acc[0] = fmaf(x0.x, wv, acc[0]); acc[1] = fmaf(x0.y, wv, acc[1]);
        acc[2] = fmaf(x0.z, wv, acc[2]); acc[3] = fmaf(x0.w, wv, acc[3]);
        acc[4] = fmaf(x1.x, wv, acc[4]); acc[5] = fmaf(x1.y, wv, acc[5]);
        acc[6] = fmaf(x1.z, wv, acc[6]); acc[7] = fmaf(x1.w, wv, acc[7]);
      }
      __syncthreads();
    }
#pragma unroll
    for (int i = 0; i < 8; ++i) zxbuf[ty * 8 + i][tx] = acc[i] + biasv;
    __syncthreads();

    // ================= Phase B: recurrence over the chunk =================
#pragma unroll 1
    for (int tl = 0; tl < CH; ++tl) {
      const int t = c * CH + tl;
      const float* rbuf = hbuf[t & 1];

      // x-part for this step: lane ln<4 holds piece ln's zx value.
      float zxv = (ln < 4) ? zxbuf[tl][ln * 4 + w] : 0.f;
      float a0 = (ln == 0) ? zxv : 0.f;
      float a1 = (ln == 1) ? zxv : 0.f;
      float a2 = (ln == 2) ? zxv : 0.f;
      float a3 = (ln == 3) ? zxv : 0.f;

#define DOTG(g, WA, WB, WC, WD) do { \
      float4 h4 = *(const float4*)&rbuf[(g) * 256 + ln * 4]; \
      a0 = fmaf(h4.x, WA.x, a0); a0 = fmaf(h4.y, WA.y, a0); \
      a0 = fmaf(h4.z, WA.z, a0); a0 = fmaf(h4.w, WA.w, a0); \
      a1 = fmaf(h4.x, WB.x, a1); a1 = fmaf(h4.y, WB.y, a1); \
      a1 = fmaf(h4.z, WB.z, a1); a1 = fmaf(h4.w, WB.w, a1); \
      a2 = fmaf(h4.x, WC.x, a2); a2 = fmaf(h4.y, WC.y, a2); \
      a2 = fmaf(h4.z, WC.z, a2); a2 = fmaf(h4.w, WC.w, a2); \
      a3 = fmaf(h4.x, WD.x, a3); a3 = fmaf(h4.y, WD.y, a3); \
      a3 = fmaf(h4.z, WD.z, a3); a3 = fmaf(h4.w, WD.w, a3); \
    } while (0)
      DOTG(0, wA0, wB0, wC0, wD0);
      DOTG(1, wA1, wB1, wC1, wD1);
      DOTG(2, wA2, wB2, wC2, wD2);
      DOTG(3, wA3, wB3, wC3, wD3);
#undef DOTG

      a0 = wave_allreduce_add(a0);
      a1 = wave_allreduce_add(a1);
      a2 = wave_allreduce_add(a2);
      a3 = wave_allreduce_add(a3);

      float f1 = fast_tanh(a0);
      float f2 = fast_tanh(a1);
      float g  = 1.f / (1.f + __expf(a2 * dtv - a3));
      float h  = fmaf(g, f1 - f2, f2);

      if (ln == 0) hq[w] = h;
      if (l == 3 && t == TT - 1 && ln == 0 && out_last) out_last[col] = h;
      __syncthreads();   // hq ready; hbuf[t&1] reads done

      // One 16B agent store per replica (wave 0, lanes 0..R-1).
      if (w == 0 && ln < R) {
        float* dst = HB + (size_t)(l * R + ln) * TT * DD + (size_t)t * DD + grp * 4;
        agent_store16(dst, *(const float4*)hq);
      }

      // Poll h(t) (all 256 threads, 16B each, per-lane early-out) into the
      // other buffer.
      if (t < TT - 1) {
        const float* src = &hread[(size_t)t * DD + tid * 4];
        float4 v = make_float4(0.f, 0.f, 0.f, 0.f);
        bool ok = false;
        int guard = 0;
        while (true) {
          if (!ok) {
            v = agent_load16(src);
            unsigned x0 = __float_as_uint(v.x) & 0x7fffffffu;
            unsigned x1 = __float_as_uint(v.y) & 0x7fffffffu;
            unsigned x2 = __float_as_uint(v.z) & 0x7fffffffu;
            unsigned x3 = __float_as_uint(v.w) & 0x7fffffffu;
            ok = (x0 <= 0x7f800000u) && (x1 <= 0x7f800000u) &&
                 (x2 <= 0x7f800000u) && (x3 <= 0x7f800000u);
          }
          if (__all(ok)) break;
          if (++guard > GUARD_LIM) break;
        }
        if (!ok) v = make_float4(0.f, 0.f, 0.f, 0.f);   // degrade, don't hang
        *(float4*)&hbuf[(t + 1) & 1][tid * 4] = v;
      }
      __syncthreads();
    }
  }
}

extern "C" void kernel_launch(void* const* d_in, const int* in_sizes, int n_in,
                              void* d_out, int out_size, void* d_ws, size_t ws_size,
                              hipStream_t stream) {
  const float* sp  = (const float*)d_in[0];
  const float* rn  = (const float*)d_in[1];
  const float* dt  = (const float*)d_in[2];
  const float* rw  = (const float*)d_in[3];
  const float* rb  = (const float*)d_in[4];
  const float* Wf1 = (const float*)d_in[5];
  const float* bf1 = (const float*)d_in[6];
  const float* Wf2 = (const float*)d_in[7];
  const float* bf2 = (const float*)d_in[8];
  const float* Wta = (const float*)d_in[9];
  const float* bta = (const float*)d_in[10];
  const float* Wtb = (const float*)d_in[11];
  const float* btb = (const float*)d_in[12];

  float* ws = (float*)d_ws;
  float* X0 = ws;                         // [TT, DD]
  float* HB = ws + (size_t)TT * DD;       // [NL*R][TT, DD]
  float* out = (float*)d_out;

  // Adaptive replica count (power of 2, max 8), limited by workspace size.
  int R = 1;
  for (int cand = 8; cand >= 1; cand >>= 1) {
    size_t need = sizeof(float) * (size_t)TT * DD * (size_t)(1 + NL * cand);
    if (need <= ws_size) { R = cand; break; }
  }

  // NaN-prefill all h buffers (poll protocol), then launch.
  (void)hipMemsetAsync(HB, 0xFF, sizeof(float) * (size_t)NL * R * TT * DD, stream);
  prep_kernel<<<(TT * DD) / 1024, 1024, 0, stream>>>(sp, rn, rw, rb, X0);
  persist_kernel<<<PBLK, NTHR, 0, stream>>>(X0, HB, R, Wf1, Wf2, Wta, Wtb,
      bf1, bf2, bta, btb, dt, out);
}

// Round 4
// 22271.678 us; speedup vs baseline: 1.0271x; 1.0157x over previous
//
#include <hip/hip_runtime.h>
#include <cstdint>
#include <cstddef>

// Problem constants (fixed by the reference)
#define DD 1024
#define TT 2048
#define NL 4
#define CH 128              // chunk length (timesteps) for pipelined x-GEMV
#define NCH (TT / CH)       // 16 chunks
#define NTHR 256            // 4 waves per block
#define PBLK (NL * 256)     // 1024 blocks, 4 per CU (all co-resident)
#define GUARD_LIM (1 << 20) // poll guard; substitute zeros on trip (no hang)

__device__ __forceinline__ float fast_tanh(float x) {
  float e = __expf(2.f * x);
  return 1.f - 2.f / (e + 1.f);
}

// 16B agent-scope load: bypasses the (non-coherent) per-XCD L2.
__device__ __forceinline__ float4 agent_load16(const float* p) {
  float4 r;
  asm volatile("global_load_dwordx4 %0, %1, off sc1\n\t"
               "s_waitcnt vmcnt(0)"
               : "=v"(r) : "v"(p) : "memory");
  return r;
}
// 32B agent-scope load (two dwordx4, ONE waitcnt): for post-gate bulk reads.
// NOTE: offset: immediate must precede cache flags on gfx950 (R3 fix).
__device__ __forceinline__ void agent_load32(const float* p, float4& a, float4& b) {
  asm volatile("global_load_dwordx4 %0, %2, off sc1\n\t"
               "global_load_dwordx4 %1, %2, off offset:16 sc1\n\t"
               "s_waitcnt vmcnt(0)"
               : "=v"(a), "=v"(b) : "v"(p) : "memory");
}
// 16B agent-scope store as two 8B atomic stores (4B-granule atomicity is all
// the NaN-poll protocol needs; half-visible granule still has NaN words).
__device__ __forceinline__ void agent_store16(float* p, float4 v) {
  unsigned long long lo =
      ((unsigned long long)__float_as_uint(v.y) << 32) | __float_as_uint(v.x);
  unsigned long long hi =
      ((unsigned long long)__float_as_uint(v.w) << 32) | __float_as_uint(v.z);
  __hip_atomic_store((unsigned long long*)p, lo,
                     __ATOMIC_RELAXED, __HIP_MEMORY_SCOPE_AGENT);
  __hip_atomic_store(((unsigned long long*)p) + 1, hi,
                     __ATOMIC_RELAXED, __HIP_MEMORY_SCOPE_AGENT);
}

// DPP-based wave64 all-reduce add (4 DPP hops + 2 ds_bpermute hops).
template <int CTRL>
__device__ __forceinline__ float dpp_add(float x) {
  int y = __builtin_amdgcn_update_dpp(0, __float_as_int(x), CTRL, 0xf, 0xf, true);
  return x + __int_as_float(y);
}
__device__ __forceinline__ float wave_allreduce_add(float x) {
  x = dpp_add<0xB1>(x);    // quad_perm [1,0,3,2]  : + lane^1
  x = dpp_add<0x4E>(x);    // quad_perm [2,3,0,1]  : + lane^2
  x = dpp_add<0x141>(x);   // row_half_mirror      : + lane^7
  x = dpp_add<0x140>(x);   // row_mirror           : + lane^15
  x += __shfl_xor(x, 16, 64);
  x += __shfl_xor(x, 32, 64);
  return x;
}

__device__ __forceinline__ bool nan_free4(float4 v) {
  unsigned x0 = __float_as_uint(v.x) & 0x7fffffffu;
  unsigned x1 = __float_as_uint(v.y) & 0x7fffffffu;
  unsigned x2 = __float_as_uint(v.z) & 0x7fffffffu;
  unsigned x3 = __float_as_uint(v.w) & 0x7fffffffu;
  return (x0 <= 0x7f800000u) && (x1 <= 0x7f800000u) &&
         (x2 <= 0x7f800000u) && (x3 <= 0x7f800000u);
}

__global__ __launch_bounds__(1024) void prep_kernel(
    const float* __restrict__ sp, const float* __restrict__ rn_p,
    const float* __restrict__ w, const float* __restrict__ b,
    float* __restrict__ X0) {
  int i = blockIdx.x * blockDim.x + threadIdx.x;   // over T*D
  float rn = rn_p[0];
  int c = i & (DD - 1);
  X0[i] = sp[i] + rn * w[c] + b[c];
}

// Persistent pipelined kernel: all 4 layers run concurrently (layer l lags
// layer l-1 by ~1 chunk). Block b: layer l = b&3, column group grp = b>>2.
// Per chunk:
//   Gate (l>=1): poll ONLY the last row of the upstream chunk (per-lane
//     early-out + s_sleep backoff). Column-owners write rows in order, so
//     last-row-complete => whole chunk complete (stores ~300us apart).
//   Phase A (GEMV): straight-line batched sc1 reads (no spinning).
//   Phase B (recurrence): wave-per-column, weights in 16 named float4 VGPRs,
//     DPP allreduce, gate math, 16B gathered agent store per replica, then
//     NaN-poll (early-out + backoff) of h(t) into the LDS double buffer.
__global__ __launch_bounds__(NTHR, 4) void persist_kernel(
    const float* __restrict__ X0,   // [TT, DD] (valid at launch)
    float* __restrict__ HB,         // [NL*R][TT, DD], NaN-prefilled
    int R,                          // replicas per layer, power of 2, >=1
    const float* __restrict__ Wf1, const float* __restrict__ Wf2,
    const float* __restrict__ Wta, const float* __restrict__ Wtb,
    const float* __restrict__ bf1, const float* __restrict__ bf2,
    const float* __restrict__ bta, const float* __restrict__ btb,
    const float* __restrict__ dt_p,
    float* __restrict__ out_last)   // [DD], written by layer 3 at t=TT-1
{
  __shared__ __align__(16) float hbuf[2][DD];   // 8 KB h double buffer
  __shared__ float zxbuf[CH][16];               // 8 KB per-chunk x-part
  __shared__ float Xs[16][132];                 // GEMV x tile (transposed)
  __shared__ float Ws[16][16];                  // GEMV weight tile
  __shared__ __align__(16) float hq[4];         // h gather across waves

  const int tid = threadIdx.x;
  const int w   = tid >> 6;             // wave 0..3 = column offset
  const int ln  = tid & 63;
  const int l   = blockIdx.x & 3;       // layer
  const int grp = blockIdx.x >> 2;      // column group 0..255
  const int col = grp * 4 + w;
  const float dtv = dt_p[0];

  const size_t woff = (size_t)l * 2 * DD * DD;

  // ---- h-part weight preload into 16 NAMED float4 regs (64 VGPRs).
  float4 wA0, wA1, wA2, wA3, wB0, wB1, wB2, wB3;
  float4 wC0, wC1, wC2, wC3, wD0, wD1, wD2, wD3;
#define LOADW(dst, base, g) do { \
    const float* p_ = (base) + (size_t)(DD + (g) * 256 + ln * 4) * DD + col; \
    dst = make_float4(p_[0], p_[DD], p_[2 * DD], p_[3 * DD]); \
  } while (0)
  {
    const float* W_ = Wf1 + woff;
    LOADW(wA0, W_, 0); LOADW(wA1, W_, 1); LOADW(wA2, W_, 2); LOADW(wA3, W_, 3);
    W_ = Wf2 + woff;
    LOADW(wB0, W_, 0); LOADW(wB1, W_, 1); LOADW(wB2, W_, 2); LOADW(wB3, W_, 3);
    W_ = Wta + woff;
    LOADW(wC0, W_, 0); LOADW(wC1, W_, 1); LOADW(wC2, W_, 2); LOADW(wC3, W_, 3);
    W_ = Wtb + woff;
    LOADW(wD0, W_, 0); LOADW(wD1, W_, 1); LOADW(wD2, W_, 2); LOADW(wD3, W_, 3);
  }
#undef LOADW

  // ---- GEMV thread mapping: tx = z-col (piece p = tx>>2, col ofs tx&3),
  // ty = row-group of 8 chunk rows.
  const int tx = tid & 15;
  const int ty = tid >> 4;
  const int p  = tx >> 2;
  const float* Wxp = ((p == 0) ? Wf1 : (p == 1) ? Wf2 : (p == 2) ? Wta : Wtb) + woff;
  const float* bsp = ((p == 0) ? bf1 : (p == 1) ? bf2 : (p == 2) ? bta : btb)
                     + (size_t)l * DD;
  const int colx = grp * 4 + (tx & 3);
  const float biasv = bsp[colx];

  // Replica selection: this block reads replica (grp & (R-1)) of both its
  // own layer (recurrence polls) and layer l-1 (GEMV x reads / gate).
  const int rsel = grp & (R - 1);
  const float* hread = HB + (size_t)(l * R + rsel) * TT * DD;
  const float* xbase = (l == 0) ? X0 : HB + (size_t)((l - 1) * R + rsel) * TT * DD;

  // h_{-1} = 0
  *(float4*)&hbuf[0][tid * 4] = make_float4(0.f, 0.f, 0.f, 0.f);
  __syncthreads();

#pragma unroll 1
  for (int c = 0; c < NCH; ++c) {
    // ---- Chunk gate (l>=1): wait for last row of upstream chunk.
    if (l > 0) {
      const float* gsrc = xbase + (size_t)(c * CH + CH - 1) * DD + tid * 4;
      bool ok = false;
      int tries = 0;
      while (true) {
        if (!ok) ok = nan_free4(agent_load16(gsrc));
        if (__all(ok)) break;
        if (++tries > 2) __builtin_amdgcn_s_sleep(8);
        if (tries > GUARD_LIM) break;   // degrade, don't hang
      }
    }

    // ================= Phase A: chunk x-GEMV (no spinning) =================
    float acc[8];
#pragma unroll
    for (int i = 0; i < 8; ++i) acc[i] = 0.f;

    const int xrow = tid >> 1;          // chunk row 0..127
    const int qb   = (tid & 1) * 2;     // k-quad base (0 or 2)

#pragma unroll 1
    for (int k0 = 0; k0 < DD; k0 += 16) {
      // Weight tile [16k][16z]: one float per thread (read-only, L2-cached).
      Ws[ty][tx] = Wxp[(size_t)(k0 + ty) * DD + colx];
      // X tile [16k][128t] (transposed): 32B per thread, one waitcnt.
      const float* src = xbase + (size_t)(c * CH + xrow) * DD + k0 + qb * 4;
      float4 va, vb;
      if (l == 0) {
        va = *(const float4*)src;
        vb = *(const float4*)(src + 4);
      } else {
        agent_load32(src, va, vb);
      }
      Xs[qb * 4 + 0][xrow] = va.x; Xs[qb * 4 + 1][xrow] = va.y;
      Xs[qb * 4 + 2][xrow] = va.z; Xs[qb * 4 + 3][xrow] = va.w;
      Xs[qb * 4 + 4][xrow] = vb.x; Xs[qb * 4 + 5][xrow] = vb.y;
      Xs[qb * 4 + 6][xrow] = vb.z; Xs[qb * 4 + 7][xrow] = vb.w;
      __syncthreads();
#pragma unroll
      for (int kk = 0; kk < 16; ++kk) {
        float wv = Ws[kk][tx];
        float4 x0 = *(const float4*)&Xs[kk][ty * 8];
        float4 x1 = *(const float4*)&Xs[kk][ty * 8 + 4];
        acc[0] = fmaf(x0.x, wv, acc[0]); acc[1] = fmaf(x0.y, wv, acc[1]);
        acc[2] = fmaf(x0.z, wv, acc[2]); acc[3] = fmaf(x0.w, wv, acc[3]);
        acc[4] = fmaf(x1.x, wv, acc[4]); acc[5] = fmaf(x1.y, wv, acc[5]);
        acc[6] = fmaf(x1.z, wv, acc[6]); acc[7] = fmaf(x1.w, wv, acc[7]);
      }
      __syncthreads();
    }
#pragma unroll
    for (int i = 0; i < 8; ++i) zxbuf[ty * 8 + i][tx] = acc[i] + biasv;
    __syncthreads();

    // ================= Phase B: recurrence over the chunk =================
#pragma unroll 1
    for (int tl = 0; tl < CH; ++tl) {
      const int t = c * CH + tl;
      const float* rbuf = hbuf[t & 1];

      // x-part for this step: lane ln<4 holds piece ln's zx value.
      float zxv = (ln < 4) ? zxbuf[tl][ln * 4 + w] : 0.f;
      float a0 = (ln == 0) ? zxv : 0.f;
      float a1 = (ln == 1) ? zxv : 0.f;
      float a2 = (ln == 2) ? zxv : 0.f;
      float a3 = (ln == 3) ? zxv : 0.f;

#define DOTG(g, WA, WB, WC, WD) do { \
      float4 h4 = *(const float4*)&rbuf[(g) * 256 + ln * 4]; \
      a0 = fmaf(h4.x, WA.x, a0); a0 = fmaf(h4.y, WA.y, a0); \
      a0 = fmaf(h4.z, WA.z, a0); a0 = fmaf(h4.w, WA.w, a0); \
      a1 = fmaf(h4.x, WB.x, a1); a1 = fmaf(h4.y, WB.y, a1); \
      a1 = fmaf(h4.z, WB.z, a1); a1 = fmaf(h4.w, WB.w, a1); \
      a2 = fmaf(h4.x, WC.x, a2); a2 = fmaf(h4.y, WC.y, a2); \
      a2 = fmaf(h4.z, WC.z, a2); a2 = fmaf(h4.w, WC.w, a2); \
      a3 = fmaf(h4.x, WD.x, a3); a3 = fmaf(h4.y, WD.y, a3); \
      a3 = fmaf(h4.z, WD.z, a3); a3 = fmaf(h4.w, WD.w, a3); \
    } while (0)
      DOTG(0, wA0, wB0, wC0, wD0);
      DOTG(1, wA1, wB1, wC1, wD1);
      DOTG(2, wA2, wB2, wC2, wD2);
      DOTG(3, wA3, wB3, wC3, wD3);
#undef DOTG

      a0 = wave_allreduce_add(a0);
      a1 = wave_allreduce_add(a1);
      a2 = wave_allreduce_add(a2);
      a3 = wave_allreduce_add(a3);

      float f1 = fast_tanh(a0);
      float f2 = fast_tanh(a1);
      float g  = 1.f / (1.f + __expf(a2 * dtv - a3));
      float h  = fmaf(g, f1 - f2, f2);

      if (ln == 0) hq[w] = h;
      if (l == 3 && t == TT - 1 && ln == 0 && out_last) out_last[col] = h;
      __syncthreads();   // hq ready; hbuf[t&1] reads done

      // One 16B agent store per replica (wave 0, lanes 0..R-1); other waves
      // fall straight through to the poll.
      if (w == 0 && ln < R) {
        float* dst = HB + (size_t)(l * R + ln) * TT * DD + (size_t)t * DD + grp * 4;
        agent_store16(dst, *(const float4*)hq);
      }

      // Poll h(t) (16B per thread, per-lane early-out, backoff after 4).
      if (t < TT - 1) {
        const float* src = &hread[(size_t)t * DD + tid * 4];
        float4 v = make_float4(0.f, 0.f, 0.f, 0.f);
        bool ok = false;
        int tries = 0;
        while (true) {
          if (!ok) {
            v = agent_load16(src);
            ok = nan_free4(v);
          }
          if (__all(ok)) break;
          if (++tries > 4) __builtin_amdgcn_s_sleep(1);
          if (tries > GUARD_LIM) break;
        }
        if (!ok) v = make_float4(0.f, 0.f, 0.f, 0.f);   // degrade, don't hang
        *(float4*)&hbuf[(t + 1) & 1][tid * 4] = v;
      }
      __syncthreads();
    }
  }
}

extern "C" void kernel_launch(void* const* d_in, const int* in_sizes, int n_in,
                              void* d_out, int out_size, void* d_ws, size_t ws_size,
                              hipStream_t stream) {
  const float* sp  = (const float*)d_in[0];
  const float* rn  = (const float*)d_in[1];
  const float* dt  = (const float*)d_in[2];
  const float* rw  = (const float*)d_in[3];
  const float* rb  = (const float*)d_in[4];
  const float* Wf1 = (const float*)d_in[5];
  const float* bf1 = (const float*)d_in[6];
  const float* Wf2 = (const float*)d_in[7];
  const float* bf2 = (const float*)d_in[8];
  const float* Wta = (const float*)d_in[9];
  const float* bta = (const float*)d_in[10];
  const float* Wtb = (const float*)d_in[11];
  const float* btb = (const float*)d_in[12];

  float* ws = (float*)d_ws;
  float* X0 = ws;                         // [TT, DD]
  float* HB = ws + (size_t)TT * DD;       // [NL*R][TT, DD]
  float* out = (float*)d_out;

  // Adaptive replica count (power of 2, max 8), limited by workspace size.
  int R = 1;
  for (int cand = 8; cand >= 1; cand >>= 1) {
    size_t need = sizeof(float) * (size_t)TT * DD * (size_t)(1 + NL * cand);
    if (need <= ws_size) { R = cand; break; }
  }

  // NaN-prefill all h buffers (poll protocol), then launch.
  (void)hipMemsetAsync(HB, 0xFF, sizeof(float) * (size_t)NL * R * TT * DD, stream);
  prep_kernel<<<(TT * DD) / 1024, 1024, 0, stream>>>(sp, rn, rw, rb, X0);
  persist_kernel<<<PBLK, NTHR, 0, stream>>>(X0, HB, R, Wf1, Wf2, Wta, Wtb,
      bf1, bf2, bta, btb, dt, out);
}

// Round 5
// 11036.397 us; speedup vs baseline: 2.0727x; 2.0180x over previous
//
#include <hip/hip_runtime.h>
#include <cstdint>
#include <cstddef>

// Problem constants (fixed by the reference)
#define DD 1024
#define TT 2048
#define NL 4
#define CH 128              // chunk length (timesteps) for pipelined x-GEMV
#define NCH (TT / CH)       // 16 chunks
#define NTHR 1024           // 16 waves per block
#define BPL 64              // blocks per layer (16 cols each)
#define PBLK (NL * BPL)     // 256 blocks = 1 per CU (LDS-forced)
#define GUARD_LIM (1 << 20) // poll guard; substitute zeros on trip (no hang)

__device__ __forceinline__ float fast_tanh(float x) {
  float e = __expf(2.f * x);
  return 1.f - 2.f / (e + 1.f);
}

// 16B agent-scope load: bypasses the (non-coherent) per-XCD L2.
__device__ __forceinline__ float4 agent_load16(const float* p) {
  float4 r;
  asm volatile("global_load_dwordx4 %0, %1, off sc1\n\t"
               "s_waitcnt vmcnt(0)"
               : "=v"(r) : "v"(p) : "memory");
  return r;
}
// 16B agent-scope store as two 8B atomic stores (4B-granule atomicity is all
// the NaN-poll protocol needs; half-visible granule still has NaN words).
__device__ __forceinline__ void agent_store16(float* p, float4 v) {
  unsigned long long lo =
      ((unsigned long long)__float_as_uint(v.y) << 32) | __float_as_uint(v.x);
  unsigned long long hi =
      ((unsigned long long)__float_as_uint(v.w) << 32) | __float_as_uint(v.z);
  __hip_atomic_store((unsigned long long*)p, lo,
                     __ATOMIC_RELAXED, __HIP_MEMORY_SCOPE_AGENT);
  __hip_atomic_store(((unsigned long long*)p) + 1, hi,
                     __ATOMIC_RELAXED, __HIP_MEMORY_SCOPE_AGENT);
}

// DPP-based wave64 all-reduce add (4 DPP hops + 2 ds_bpermute hops).
template <int CTRL>
__device__ __forceinline__ float dpp_add(float x) {
  int y = __builtin_amdgcn_update_dpp(0, __float_as_int(x), CTRL, 0xf, 0xf, true);
  return x + __int_as_float(y);
}
__device__ __forceinline__ float wave_allreduce_add(float x) {
  x = dpp_add<0xB1>(x);    // quad_perm [1,0,3,2]  : + lane^1
  x = dpp_add<0x4E>(x);    // quad_perm [2,3,0,1]  : + lane^2
  x = dpp_add<0x141>(x);   // row_half_mirror      : + lane^7
  x = dpp_add<0x140>(x);   // row_mirror           : + lane^15
  x += __shfl_xor(x, 16, 64);
  x += __shfl_xor(x, 32, 64);
  return x;
}

__device__ __forceinline__ bool nan_free4(float4 v) {
  unsigned x0 = __float_as_uint(v.x) & 0x7fffffffu;
  unsigned x1 = __float_as_uint(v.y) & 0x7fffffffu;
  unsigned x2 = __float_as_uint(v.z) & 0x7fffffffu;
  unsigned x3 = __float_as_uint(v.w) & 0x7fffffffu;
  return (x0 <= 0x7f800000u) && (x1 <= 0x7f800000u) &&
         (x2 <= 0x7f800000u) && (x3 <= 0x7f800000u);
}

__global__ __launch_bounds__(1024) void prep_kernel(
    const float* __restrict__ sp, const float* __restrict__ rn_p,
    const float* __restrict__ w, const float* __restrict__ b,
    float* __restrict__ X0) {
  int i = blockIdx.x * blockDim.x + threadIdx.x;   // over T*D
  float rn = rn_p[0];
  int c = i & (DD - 1);
  X0[i] = sp[i] + rn * w[c] + b[c];
}

// Persistent pipelined kernel, 1 block per CU.
// Block b: layer l = b>>6 (each layer's 64 blocks spread over all 8 XCDs,
// one block per CU — LDS >80KB forces single residency), column group
// grp = b&63 (columns grp*16 .. grp*16+15). 16 waves; wave w owns column
// col = grp*16 + w for the recurrence, with its h-part weights (4 pieces x
// 16 rows/lane) in 16 named float4 VGPRs.
// Per chunk:
//   Gate (l>=1): waves 0-3 poll the LAST row of the upstream chunk
//     (early-out + s_sleep), then __syncthreads. Producers write rows in
//     order with vmcnt-drained barriers per step => last-row => chunk done.
//   Phase A (GEMV): zx[t][p*16+cofs] for the chunk, straight-line sc1 reads.
//   Phase B (recurrence): 128 steps; DOTG from LDS h-broadcast, DPP
//     allreduce, gate math; 64B h message per replica (wave 0); waves 0-3
//     poll h(t) into the double buffer.
__global__ __launch_bounds__(NTHR, 4) void persist_kernel(
    const float* __restrict__ X0,   // [TT, DD] (valid at launch)
    float* __restrict__ HB,         // [NL*R][TT, DD], NaN-prefilled
    int R,                          // replicas per layer, power of 2, >=1
    const float* __restrict__ Wf1, const float* __restrict__ Wf2,
    const float* __restrict__ Wta, const float* __restrict__ Wtb,
    const float* __restrict__ bf1, const float* __restrict__ bf2,
    const float* __restrict__ bta, const float* __restrict__ btb,
    const float* __restrict__ dt_p,
    float* __restrict__ out_last)   // [DD], written by layer 3 at t=TT-1
{
  __shared__ __align__(16) float hbuf[2][DD];   // 8 KB h double buffer
  __shared__ float zxbuf[CH][64];               // 32 KB per-chunk x-part
  __shared__ float Xs[16][132];                 // 8.4 KB GEMV x tile
  __shared__ float Ws[16][64];                  // 4 KB GEMV weight tile
  __shared__ __align__(64) float hq[16];        // h gather across waves
  __shared__ float lds_pad[7424];               // 29.7 KB: total >80KB => 1 blk/CU

  const int tid = threadIdx.x;
  const int w   = tid >> 6;             // wave 0..15 = column offset
  const int ln  = tid & 63;
  const int l   = blockIdx.x >> 6;      // layer (64 consecutive blocks each)
  const int grp = blockIdx.x & 63;      // column group 0..63
  const int col = grp * 16 + w;
  const float dtv = dt_p[0];

  lds_pad[tid] = 0.f;                   // keep the pad allocated

  const size_t woff = (size_t)l * 2 * DD * DD;

  // ---- h-part weight preload into 16 NAMED float4 regs (64 VGPRs).
  float4 wA0, wA1, wA2, wA3, wB0, wB1, wB2, wB3;
  float4 wC0, wC1, wC2, wC3, wD0, wD1, wD2, wD3;
#define LOADW(dst, base, g) do { \
    const float* p_ = (base) + (size_t)(DD + (g) * 256 + ln * 4) * DD + col; \
    dst = make_float4(p_[0], p_[DD], p_[2 * DD], p_[3 * DD]); \
  } while (0)
  {
    const float* W_ = Wf1 + woff;
    LOADW(wA0, W_, 0); LOADW(wA1, W_, 1); LOADW(wA2, W_, 2); LOADW(wA3, W_, 3);
    W_ = Wf2 + woff;
    LOADW(wB0, W_, 0); LOADW(wB1, W_, 1); LOADW(wB2, W_, 2); LOADW(wB3, W_, 3);
    W_ = Wta + woff;
    LOADW(wC0, W_, 0); LOADW(wC1, W_, 1); LOADW(wC2, W_, 2); LOADW(wC3, W_, 3);
    W_ = Wtb + woff;
    LOADW(wD0, W_, 0); LOADW(wD1, W_, 1); LOADW(wD2, W_, 2); LOADW(wD3, W_, 3);
  }
#undef LOADW

  // ---- GEMV thread mapping: zc = ln (piece p = ln>>4, col ofs ln&15),
  // row-group = w (8 rows each).
  const int p  = ln >> 4;
  const float* Wxp = ((p == 0) ? Wf1 : (p == 1) ? Wf2 : (p == 2) ? Wta : Wtb) + woff;
  const float* bsp = ((p == 0) ? bf1 : (p == 1) ? bf2 : (p == 2) ? bta : btb)
                     + (size_t)l * DD;
  const int colx = grp * 16 + (ln & 15);
  const float biasv = bsp[colx];

  // Replica selection.
  const int rsel = grp & (R - 1);
  const float* hread = HB + (size_t)(l * R + rsel) * TT * DD;
  const float* xbase = (l == 0) ? X0 : HB + (size_t)((l - 1) * R + rsel) * TT * DD;

  // h_{-1} = 0
  hbuf[0][tid] = 0.f;
  __syncthreads();

#pragma unroll 1
  for (int c = 0; c < NCH; ++c) {
    // ---- Chunk gate (l>=1): waves 0-3 wait for last row of upstream chunk.
    if (l > 0) {
      if (tid < 256) {
        const float* gsrc = xbase + (size_t)(c * CH + CH - 1) * DD + tid * 4;
        bool ok = false;
        int tries = 0;
        while (true) {
          if (!ok) ok = nan_free4(agent_load16(gsrc));
          if (__all(ok)) break;
          if (++tries > 2) __builtin_amdgcn_s_sleep(8);
          if (tries > GUARD_LIM) break;   // degrade, don't hang
        }
      }
      __syncthreads();
    }

    // ================= Phase A: chunk x-GEMV (no spinning) =================
    float acc[8];
#pragma unroll
    for (int i = 0; i < 8; ++i) acc[i] = 0.f;

#pragma unroll 1
    for (int k0 = 0; k0 < DD; k0 += 16) {
      // Weight tile [16k][64z]: one float per thread.
      Ws[w][ln] = Wxp[(size_t)(k0 + w) * DD + colx];
      // X tile [16k][128t] (transposed): waves 0-7, 16B per thread.
      if (tid < 512) {
        const int row = tid >> 2;          // 0..127
        const int q   = (tid & 3) * 4;     // k-quad
        const float* src = xbase + (size_t)(c * CH + row) * DD + k0 + q;
        float4 v = (l == 0) ? *(const float4*)src : agent_load16(src);
        Xs[q + 0][row] = v.x; Xs[q + 1][row] = v.y;
        Xs[q + 2][row] = v.z; Xs[q + 3][row] = v.w;
      }
      __syncthreads();
#pragma unroll
      for (int kk = 0; kk < 16; ++kk) {
        float wv = Ws[kk][ln];
        float4 x0 = *(const float4*)&Xs[kk][w * 8];       // broadcast per wave
        float4 x1 = *(const float4*)&Xs[kk][w * 8 + 4];
        acc[0] = fmaf(x0.x, wv, acc[0]); acc[1] = fmaf(x0.y, wv, acc[1]);
        acc[2] = fmaf(x0.z, wv, acc[2]); acc[3] = fmaf(x0.w, wv, acc[3]);
        acc[4] = fmaf(x1.x, wv, acc[4]); acc[5] = fmaf(x1.y, wv, acc[5]);
        acc[6] = fmaf(x1.z, wv, acc[6]); acc[7] = fmaf(x1.w, wv, acc[7]);
      }
      __syncthreads();
    }
#pragma unroll
    for (int i = 0; i < 8; ++i) zxbuf[w * 8 + i][ln] = acc[i] + biasv;
    __syncthreads();

    // ================= Phase B: recurrence over the chunk =================
#pragma unroll 1
    for (int tl = 0; tl < CH; ++tl) {
      const int t = c * CH + tl;
      const float* rbuf = hbuf[t & 1];

      // x-part: lane ln<4 holds piece ln's zx value for column w.
      float zxv = (ln < 4) ? zxbuf[tl][ln * 16 + w] : 0.f;
      float a0 = (ln == 0) ? zxv : 0.f;
      float a1 = (ln == 1) ? zxv : 0.f;
      float a2 = (ln == 2) ? zxv : 0.f;
      float a3 = (ln == 3) ? zxv : 0.f;

#define DOTG(g, WA, WB, WC, WD) do { \
      float4 h4 = *(const float4*)&rbuf[(g) * 256 + ln * 4]; \
      a0 = fmaf(h4.x, WA.x, a0); a0 = fmaf(h4.y, WA.y, a0); \
      a0 = fmaf(h4.z, WA.z, a0); a0 = fmaf(h4.w, WA.w, a0); \
      a1 = fmaf(h4.x, WB.x, a1); a1 = fmaf(h4.y, WB.y, a1); \
      a1 = fmaf(h4.z, WB.z, a1); a1 = fmaf(h4.w, WB.w, a1); \
      a2 = fmaf(h4.x, WC.x, a2); a2 = fmaf(h4.y, WC.y, a2); \
      a2 = fmaf(h4.z, WC.z, a2); a2 = fmaf(h4.w, WC.w, a2); \
      a3 = fmaf(h4.x, WD.x, a3); a3 = fmaf(h4.y, WD.y, a3); \
      a3 = fmaf(h4.z, WD.z, a3); a3 = fmaf(h4.w, WD.w, a3); \
    } while (0)
      DOTG(0, wA0, wB0, wC0, wD0);
      DOTG(1, wA1, wB1, wC1, wD1);
      DOTG(2, wA2, wB2, wC2, wD2);
      DOTG(3, wA3, wB3, wC3, wD3);
#undef DOTG

      a0 = wave_allreduce_add(a0);
      a1 = wave_allreduce_add(a1);
      a2 = wave_allreduce_add(a2);
      a3 = wave_allreduce_add(a3);

      float f1 = fast_tanh(a0);
      float f2 = fast_tanh(a1);
      float g  = 1.f / (1.f + __expf(a2 * dtv - a3));
      float h  = fmaf(g, f1 - f2, f2);

      if (ln == 0) hq[w] = h;
      if (l == 3 && t == TT - 1 && ln == 0 && out_last) out_last[col] = h;
      __syncthreads();   // hq ready

      // One 64B message per replica (wave 0, lanes 0..R-1).
      if (w == 0 && ln < R) {
        float* dst = HB + (size_t)(l * R + ln) * TT * DD + (size_t)t * DD + grp * 16;
        float4 q0 = *(const float4*)&hq[0];
        float4 q1 = *(const float4*)&hq[4];
        float4 q2 = *(const float4*)&hq[8];
        float4 q3 = *(const float4*)&hq[12];
        agent_store16(dst + 0,  q0);
        agent_store16(dst + 4,  q1);
        agent_store16(dst + 8,  q2);
        agent_store16(dst + 12, q3);
      }

      // Poll h(t): waves 0-3 (16B per thread, early-out, backoff).
      if (t < TT - 1 && tid < 256) {
        const float* src = &hread[(size_t)t * DD + tid * 4];
        float4 v = make_float4(0.f, 0.f, 0.f, 0.f);
        bool ok = false;
        int tries = 0;
        while (true) {
          if (!ok) {
            v = agent_load16(src);
            ok = nan_free4(v);
          }
          if (__all(ok)) break;
          if (++tries > 8) __builtin_amdgcn_s_sleep(1);
          if (tries > GUARD_LIM) break;
        }
        if (!ok) v = make_float4(0.f, 0.f, 0.f, 0.f);   // degrade, don't hang
        *(float4*)&hbuf[(t + 1) & 1][tid * 4] = v;
      }
      __syncthreads();
    }
  }
}

extern "C" void kernel_launch(void* const* d_in, const int* in_sizes, int n_in,
                              void* d_out, int out_size, void* d_ws, size_t ws_size,
                              hipStream_t stream) {
  const float* sp  = (const float*)d_in[0];
  const float* rn  = (const float*)d_in[1];
  const float* dt  = (const float*)d_in[2];
  const float* rw  = (const float*)d_in[3];
  const float* rb  = (const float*)d_in[4];
  const float* Wf1 = (const float*)d_in[5];
  const float* bf1 = (const float*)d_in[6];
  const float* Wf2 = (const float*)d_in[7];
  const float* bf2 = (const float*)d_in[8];
  const float* Wta = (const float*)d_in[9];
  const float* bta = (const float*)d_in[10];
  const float* Wtb = (const float*)d_in[11];
  const float* btb = (const float*)d_in[12];

  float* ws = (float*)d_ws;
  float* X0 = ws;                         // [TT, DD]
  float* HB = ws + (size_t)TT * DD;       // [NL*R][TT, DD]
  float* out = (float*)d_out;

  // Adaptive replica count (power of 2, max 8), limited by workspace size.
  int R = 1;
  for (int cand = 8; cand >= 1; cand >>= 1) {
    size_t need = sizeof(float) * (size_t)TT * DD * (size_t)(1 + NL * cand);
    if (need <= ws_size) { R = cand; break; }
  }

  // NaN-prefill all h buffers (poll protocol), then launch.
  (void)hipMemsetAsync(HB, 0xFF, sizeof(float) * (size_t)NL * R * TT * DD, stream);
  prep_kernel<<<(TT * DD) / 1024, 1024, 0, stream>>>(sp, rn, rw, rb, X0);
  persist_kernel<<<PBLK, NTHR, 0, stream>>>(X0, HB, R, Wf1, Wf2, Wta, Wtb,
      bf1, bf2, bta, btb, dt, out);
}